// Round 11
// baseline (1698.669 us; speedup 1.0000x reference)
//
#include <hip/hip_runtime.h>
#include <math.h>

// Problem constants (reference: MAB block, B=4, N=1024, D=1024, H=16)
#define BATCH 4
#define NQL   1024
#define NKL   1024
#define DIM   1024
#define NHEAD 16
#define DHEAD 64
#define SCALE 0.03125f      // 1/sqrt(DIM)

typedef float  f32x4  __attribute__((ext_vector_type(4)));
typedef short  short8 __attribute__((ext_vector_type(8)));

__device__ __forceinline__ ushort f2bf(float x) {
    uint u = __float_as_uint(x);
    u += 0x7FFFu + ((u >> 16) & 1u);
    return (ushort)(u >> 16);
}
__device__ __forceinline__ float bf2f(ushort h) {
    return __uint_as_float(((uint)h) << 16);
}

// ===========================================================================
// split_bf: x (fp32) -> hi = bf16(x), lo = bf16(x - hi).  n4 = n/4.
// ===========================================================================
__global__ __launch_bounds__(256)
void split_bf(const float* __restrict__ x, ushort* __restrict__ hi,
              ushort* __restrict__ lo, int n4)
{
    const int i = blockIdx.x * 256 + threadIdx.x;
    if (i >= n4) return;
    const float4 v = ((const float4*)x)[i];
    ushort4 h, l;
    h.x = f2bf(v.x); l.x = f2bf(v.x - bf2f(h.x));
    h.y = f2bf(v.y); l.y = f2bf(v.y - bf2f(h.y));
    h.z = f2bf(v.z); l.z = f2bf(v.z - bf2f(h.z));
    h.w = f2bf(v.w); l.w = f2bf(v.w - bf2f(h.w));
    ((ushort4*)hi)[i] = h;
    ((ushort4*)lo)[i] = l;
}

// ===========================================================================
// gemm_mfma v2 (round 8 counters: 1 block/CU, MfmaUtil 11%, all pipes idle ->
// latency-bound at grid=256. Re-tiled for occupancy):
//   64x64 tile, 4 waves (2x2 of 32x32), BK=64, 36KB LDS, grid 1024-2048
//   blocks -> 4 blocks/CU (~50% occupancy), 4 independent barrier chains.
// bf16x3 split runs as 3 K-phases over the SAME accumulator:
//   phase0: Ahi*Bhi   phase1: Ahi*Blo   phase2: Alo*Bhi
// (pointer swap per phase; NPROD=1 -> single phase.)
// LDS row stride 72 ushort = 36 dwords == 4 (mod 32): fragment reads AND
// staging writes both uniform 2-way per 16-lane phase (free).
// C/D layout (HW-validated r5): col=lane&15, row=(lane>>4)*4+reg.
// OMODE: 0 fp32 C; 1 fp32 C + bf16-hi; 2 bf16-hi only; 3 Vt[(h*4+b)][d][key].
// ===========================================================================
#define LDK2 72

template<int NPROD, int BIAS, int RESID, int OMODE>
__global__ __launch_bounds__(256, 4)
void gemm_mfma(const ushort* __restrict__ Ahi, const ushort* __restrict__ Alo,
               int lda,
               const ushort* __restrict__ Bhi, const ushort* __restrict__ Blo,
               int ldb,
               const float* __restrict__ bias,
               const float* __restrict__ rm,
               float* __restrict__ Cm, ushort* __restrict__ Chi,
               int ldc, int Kd, float scale)
{
    __shared__ ushort As_[2][64 * LDK2];
    __shared__ ushort Bs_[2][64 * LDK2];

    const int tid  = threadIdx.x;
    const int lane = tid & 63;
    const int wid  = tid >> 6;
    const int wr   = wid >> 1, wc = wid & 1;   // wave's 32x32 sub-tile
    const int l15  = lane & 15;
    const int lg   = lane >> 4;
    const int bm   = blockIdx.x * 64;
    const int bn   = blockIdx.y * 64;

    const int tpp = Kd >> 6;                   // K-tiles per phase
    const int nt  = NPROD * tpp;

    int4 ra[2], rb[2];
    auto gload = [&](int t) {
        const ushort* Asrc = Ahi;
        const ushort* Bsrc = Bhi;
        int tt = t;
        if constexpr (NPROD == 3) {
            if (t >= 2 * tpp)  { Asrc = Alo; tt = t - 2 * tpp; }
            else if (t >= tpp) { Bsrc = Blo; tt = t - tpp; }
        }
        const int k0 = tt << 6;
#pragma unroll
        for (int p = 0; p < 2; ++p) {
            const int idx = p * 256 + tid;          // 512 16B chunks per tile
            const int row = idx >> 3, col = (idx & 7) << 3;
            ra[p] = *(const int4*)(Asrc + (size_t)(bm + row) * lda + k0 + col);
            rb[p] = *(const int4*)(Bsrc + (size_t)(bn + row) * ldb + k0 + col);
        }
    };
    auto dswrite = [&](int buf) {
#pragma unroll
        for (int p = 0; p < 2; ++p) {
            const int idx = p * 256 + tid;
            const int row = idx >> 3, col = (idx & 7) << 3;
            *(int4*)&As_[buf][row * LDK2 + col] = ra[p];
            *(int4*)&Bs_[buf][row * LDK2 + col] = rb[p];
        }
    };

    gload(0); dswrite(0); __syncthreads();

    f32x4 acc[2][2] = {};
    int cur = 0;

    for (int t = 0; t < nt; ++t) {
        const bool more = (t + 1) < nt;
        if (more) gload(t + 1);           // issue next tile early

        short8 ah[2][2], bh[2][2];
#pragma unroll
        for (int f = 0; f < 2; ++f)
#pragma unroll
            for (int ks = 0; ks < 2; ++ks) {
                ah[f][ks] = *(const short8*)&As_[cur][(wr * 32 + f * 16 + l15) * LDK2 + ks * 32 + lg * 8];
                bh[f][ks] = *(const short8*)&Bs_[cur][(wc * 32 + f * 16 + l15) * LDK2 + ks * 32 + lg * 8];
            }
#pragma unroll
        for (int fi = 0; fi < 2; ++fi)
#pragma unroll
            for (int fj = 0; fj < 2; ++fj) {
                acc[fi][fj] = __builtin_amdgcn_mfma_f32_16x16x32_bf16(ah[fi][0], bh[fj][0], acc[fi][fj], 0, 0, 0);
                acc[fi][fj] = __builtin_amdgcn_mfma_f32_16x16x32_bf16(ah[fi][1], bh[fj][1], acc[fi][fj], 0, 0, 0);
            }

        if (more) dswrite(cur ^ 1);       // other buffer; one barrier/K-step
        __syncthreads();
        cur ^= 1;
    }

    // epilogue
    float biasv[2];
    if (BIAS) {
#pragma unroll
        for (int fj = 0; fj < 2; ++fj)
            biasv[fj] = bias[bn + wc * 32 + fj * 16 + l15];
    }
#pragma unroll
    for (int fi = 0; fi < 2; ++fi) {
        const int r0 = bm + wr * 32 + fi * 16 + (lg << 2);
#pragma unroll
        for (int fj = 0; fj < 2; ++fj) {
            const int c = bn + wc * 32 + fj * 16 + l15;
            if constexpr (OMODE == 3) {
                ushort4 v4;
#pragma unroll
                for (int r = 0; r < 4; ++r) {
                    float o = acc[fi][fj][r] * scale;
                    if (BIAS) o += biasv[fj];
                    ((ushort*)&v4)[r] = f2bf(o);
                }
                const int b   = r0 >> 10;
                const int key = r0 & 1023;
                const int h   = c >> 6;
                const int d   = c & 63;
                *(ushort4*)(Chi + ((size_t)((h << 2) + b) << 16) + (size_t)d * 1024 + key) = v4;
            } else {
#pragma unroll
                for (int r = 0; r < 4; ++r) {
                    float o = acc[fi][fj][r] * scale;
                    if (BIAS) o += biasv[fj];
                    if (RESID) o += rm[(size_t)(r0 + r) * ldc + c];
                    if (OMODE == 0 || OMODE == 1)
                        Cm[(size_t)(r0 + r) * ldc + c] = o;
                    if (OMODE == 1 || OMODE == 2)
                        Chi[(size_t)(r0 + r) * ldc + c] = f2bf(o);
                }
            }
        }
    }
}

// ===========================================================================
// flash_attn: per block = 128 q-rows x one hb (h*4+b). grid (8, 64), 4 waves.
// (unchanged from the r8-validated kernel; not in top-5 dispatches)
// ===========================================================================
__global__ __launch_bounds__(256)
void flash_attn(const ushort* __restrict__ QpHi,  // [4][1024][1024]
                const ushort* __restrict__ KpHi,  // [4][1024][1024]
                const ushort* __restrict__ Vt,    // [64][64][1024]
                const float*  __restrict__ Qp,    // [4][1024][1024] residual
                float* __restrict__ Aout,         // [64][1024][1024]
                float* __restrict__ Oa)           // [4][1024][1024]
{
    __shared__ ushort Ks[2][64][72];
    __shared__ ushort Vs[2][64][72];
    __shared__ ushort Ps[4][32][72];

    const int tid  = threadIdx.x;
    const int lane = tid & 63;
    const int w    = tid >> 6;
    const int l15  = lane & 15;
    const int lg   = lane >> 4;
    const int bm   = blockIdx.x * 128;
    const int hb   = blockIdx.y;
    const int zh   = hb >> 2, zb = hb & 3;

    const ushort* Qb  = QpHi + ((size_t)zb << 20) + zh * 64;
    const ushort* Kb  = KpHi + ((size_t)zb << 20) + zh * 64;
    const ushort* Vtb = Vt   + ((size_t)hb << 16);
    const float*  Qrb = Qp   + ((size_t)zb << 20) + zh * 64 + (size_t)bm * DIM;
    float* Ab = Aout + ((size_t)hb << 20) + (size_t)bm * NKL;
    float* Ob = Oa   + ((size_t)zb << 20) + zh * 64 + (size_t)bm * DIM;

    short8 qf[2][2];
#pragma unroll
    for (int qg = 0; qg < 2; ++qg)
#pragma unroll
        for (int kg = 0; kg < 2; ++kg)
            qf[qg][kg] = *(const short8*)(Qb + (size_t)(bm + w * 32 + qg * 16 + l15) * DIM
                                          + kg * 32 + lg * 8);

    int4 kreg[2], vreg[2];
    auto kload = [&](int kt) {
#pragma unroll
        for (int p = 0; p < 2; ++p) {
            const int c = p * 256 + tid;
            kreg[p] = *(const int4*)(Kb + (size_t)(kt * 64 + (c >> 3)) * DIM + (c & 7) * 8);
        }
    };
    auto kstore = [&](int buf) {
#pragma unroll
        for (int p = 0; p < 2; ++p) {
            const int c = p * 256 + tid;
            *(int4*)&Ks[buf][c >> 3][(c & 7) * 8] = kreg[p];
        }
    };
    auto vload = [&](int kt) {
#pragma unroll
        for (int p = 0; p < 2; ++p) {
            const int c = p * 256 + tid;
            vreg[p] = *(const int4*)(Vtb + (size_t)(c >> 3) * 1024 + kt * 64 + (c & 7) * 8);
        }
    };
    auto vstore = [&](int buf) {
#pragma unroll
        for (int p = 0; p < 2; ++p) {
            const int c = p * 256 + tid;
            *(int4*)&Vs[buf][c >> 3][(c & 7) * 8] = vreg[p];
        }
    };
    auto qk = [&](int buf, f32x4 (*s)[4]) {
        short8 kf[4][2];
#pragma unroll
        for (int cg = 0; cg < 4; ++cg)
#pragma unroll
            for (int kg = 0; kg < 2; ++kg)
                kf[cg][kg] = *(const short8*)&Ks[buf][cg * 16 + l15][kg * 32 + lg * 8];
#pragma unroll
        for (int qg = 0; qg < 2; ++qg)
#pragma unroll
            for (int cg = 0; cg < 4; ++cg) {
                s[qg][cg] = __builtin_amdgcn_mfma_f32_16x16x32_bf16(qf[qg][0], kf[cg][0], s[qg][cg], 0, 0, 0);
                s[qg][cg] = __builtin_amdgcn_mfma_f32_16x16x32_bf16(qf[qg][1], kf[cg][1], s[qg][cg], 0, 0, 0);
            }
    };

    // ---- pass 1: online per-lane stats ------------------------------------
    float mrun[2][4], lrun[2][4];
#pragma unroll
    for (int qg = 0; qg < 2; ++qg)
#pragma unroll
        for (int r = 0; r < 4; ++r) { mrun[qg][r] = -INFINITY; lrun[qg][r] = 0.f; }

    kload(0); kstore(0); __syncthreads();
    for (int kt = 0; kt < 16; ++kt) {
        const bool more = kt < 15;
        if (more) kload(kt + 1);
        f32x4 s[2][4] = {};
        qk(kt & 1, s);
#pragma unroll
        for (int qg = 0; qg < 2; ++qg)
#pragma unroll
            for (int r = 0; r < 4; ++r) {
                const float v0 = s[qg][0][r] * SCALE, v1 = s[qg][1][r] * SCALE;
                const float v2 = s[qg][2][r] * SCALE, v3 = s[qg][3][r] * SCALE;
                const float tm = fmaxf(fmaxf(v0, v1), fmaxf(v2, v3));
                const float mn = fmaxf(mrun[qg][r], tm);
                const float sc = __expf(mrun[qg][r] - mn);
                lrun[qg][r] = lrun[qg][r] * sc
                            + __expf(v0 - mn) + __expf(v1 - mn)
                            + __expf(v2 - mn) + __expf(v3 - mn);
                mrun[qg][r] = mn;
            }
        if (more) { kstore((kt + 1) & 1); __syncthreads(); }
    }

    float mf[2][4], li[2][4];
#pragma unroll
    for (int qg = 0; qg < 2; ++qg)
#pragma unroll
        for (int r = 0; r < 4; ++r) {
            float m = mrun[qg][r];
#pragma unroll
            for (int off = 1; off < 16; off <<= 1) m = fmaxf(m, __shfl_xor(m, off));
            float lv = lrun[qg][r] * __expf(mrun[qg][r] - m);
#pragma unroll
            for (int off = 1; off < 16; off <<= 1) lv += __shfl_xor(lv, off);
            mf[qg][r] = m;
            li[qg][r] = 1.f / lv;
        }

    // ---- pass 2: A write + PV ---------------------------------------------
    kload(0); vload(0);
    __syncthreads();
    kstore(0); vstore(0);
    __syncthreads();

    f32x4 oacc[2][4] = {};
    for (int kt = 0; kt < 16; ++kt) {
        const bool more = kt < 15;
        if (more) { kload(kt + 1); vload(kt + 1); }
        f32x4 s[2][4] = {};
        qk(kt & 1, s);

#pragma unroll
        for (int qg = 0; qg < 2; ++qg)
#pragma unroll
            for (int cg = 0; cg < 4; ++cg) {
#pragma unroll
                for (int r = 0; r < 4; ++r) {
                    const float p = __expf(s[qg][cg][r] * SCALE - mf[qg][r]) * li[qg][r];
                    Ps[w][qg * 16 + lg * 4 + r][cg * 16 + l15] = f2bf(p);
                    Ab[(size_t)(w * 32 + qg * 16 + lg * 4 + r) * NKL
                       + kt * 64 + cg * 16 + l15] = p;
                }
            }

        short8 pf[2][2], vf[4][2];
#pragma unroll
        for (int qg = 0; qg < 2; ++qg)
#pragma unroll
            for (int kk = 0; kk < 2; ++kk)
                pf[qg][kk] = *(const short8*)&Ps[w][qg * 16 + l15][kk * 32 + lg * 8];
#pragma unroll
        for (int dg = 0; dg < 4; ++dg)
#pragma unroll
            for (int kk = 0; kk < 2; ++kk)
                vf[dg][kk] = *(const short8*)&Vs[kt & 1][dg * 16 + l15][kk * 32 + lg * 8];
#pragma unroll
        for (int qg = 0; qg < 2; ++qg)
#pragma unroll
            for (int dg = 0; dg < 4; ++dg) {
                oacc[qg][dg] = __builtin_amdgcn_mfma_f32_16x16x32_bf16(pf[qg][0], vf[dg][0], oacc[qg][dg], 0, 0, 0);
                oacc[qg][dg] = __builtin_amdgcn_mfma_f32_16x16x32_bf16(pf[qg][1], vf[dg][1], oacc[qg][dg], 0, 0, 0);
            }

        if (more) { kstore((kt + 1) & 1); vstore((kt + 1) & 1); __syncthreads(); }
    }

#pragma unroll
    for (int qg = 0; qg < 2; ++qg)
#pragma unroll
        for (int dg = 0; dg < 4; ++dg)
#pragma unroll
            for (int r = 0; r < 4; ++r) {
                const size_t idx = (size_t)(w * 32 + qg * 16 + lg * 4 + r) * DIM
                                 + dg * 16 + l15;
                Ob[idx] = oacc[qg][dg][r] + Qrb[idx];
            }
}

// ===========================================================================
// Row LayerNorm (1024 cols, one block/row). SPLIT=1 also emits bf16 hi/lo.
// ===========================================================================
template<int SPLIT>
__global__ __launch_bounds__(256)
void ln_rows(const float* __restrict__ in, const float* __restrict__ g,
             const float* __restrict__ b, float* __restrict__ out,
             ushort* __restrict__ ohi, ushort* __restrict__ olo)
{
    const int row = blockIdx.x;
    const int tid = threadIdx.x;
    const float4 xv = *(const float4*)(in + (size_t)row * DIM + (tid << 2));

    float s = xv.x + xv.y + xv.z + xv.w;
    float q = xv.x * xv.x + xv.y * xv.y + xv.z * xv.z + xv.w * xv.w;
#pragma unroll
    for (int off = 32; off; off >>= 1) {
        s += __shfl_xor(s, off);
        q += __shfl_xor(q, off);
    }
    __shared__ float ss[4], qq[4];
    if ((tid & 63) == 0) { ss[tid >> 6] = s; qq[tid >> 6] = q; }
    __syncthreads();
    s = ss[0] + ss[1] + ss[2] + ss[3];
    q = qq[0] + qq[1] + qq[2] + qq[3];

    const float mu  = s * (1.f / 1024.f);
    const float var = q * (1.f / 1024.f) - mu * mu;
    const float rs  = rsqrtf(var + 1e-5f);

    const float4 gv = *(const float4*)(g + (tid << 2));
    const float4 bv = *(const float4*)(b + (tid << 2));
    float4 o;
    o.x = (xv.x - mu) * rs * gv.x + bv.x;
    o.y = (xv.y - mu) * rs * gv.y + bv.y;
    o.z = (xv.z - mu) * rs * gv.z + bv.z;
    o.w = (xv.w - mu) * rs * gv.w + bv.w;
    *(float4*)(out + (size_t)row * DIM + (tid << 2)) = o;

    if (SPLIT) {
        ushort4 h, l;
        h.x = f2bf(o.x); l.x = f2bf(o.x - bf2f(h.x));
        h.y = f2bf(o.y); l.y = f2bf(o.y - bf2f(h.y));
        h.z = f2bf(o.z); l.z = f2bf(o.z - bf2f(h.z));
        h.w = f2bf(o.w); l.w = f2bf(o.w - bf2f(h.w));
        ((ushort4*)(ohi + (size_t)row * DIM))[tid] = h;
        ((ushort4*)(olo + (size_t)row * DIM))[tid] = l;
    }
}

// ===========================================================================
// gate = silu(x1) * x2, emitted as bf16 hi/lo split.
// ===========================================================================
__global__ __launch_bounds__(256)
void silu_mul(const float* __restrict__ x12, ushort* __restrict__ ghi,
              ushort* __restrict__ glo)
{
    const int i = blockIdx.x * 256 + threadIdx.x;
    const int n = i >> 8;
    const int c = (i & 255) << 2;
    const float4 a = *(const float4*)(x12 + (size_t)n * 2048 + c);
    const float4 b = *(const float4*)(x12 + (size_t)n * 2048 + 1024 + c);
    float4 o;
    o.x = a.x / (1.f + __expf(-a.x)) * b.x;
    o.y = a.y / (1.f + __expf(-a.y)) * b.y;
    o.z = a.z / (1.f + __expf(-a.z)) * b.z;
    o.w = a.w / (1.f + __expf(-a.w)) * b.w;
    ushort4 h, l;
    h.x = f2bf(o.x); l.x = f2bf(o.x - bf2f(h.x));
    h.y = f2bf(o.y); l.y = f2bf(o.y - bf2f(h.y));
    h.z = f2bf(o.z); l.z = f2bf(o.z - bf2f(h.z));
    h.w = f2bf(o.w); l.w = f2bf(o.w - bf2f(h.w));
    ((ushort4*)ghi)[i] = h;
    ((ushort4*)glo)[i] = l;
}

// ---------------------------------------------------------------------------
extern "C" void kernel_launch(void* const* d_in, const int* in_sizes, int n_in,
                              void* d_out, int out_size, void* d_ws, size_t ws_size,
                              hipStream_t stream)
{
    const float* Q   = (const float*)d_in[0];
    const float* K   = (const float*)d_in[1];
    const float* Wq  = (const float*)d_in[2];
    const float* bq  = (const float*)d_in[3];
    const float* Wk  = (const float*)d_in[4];
    const float* bk  = (const float*)d_in[5];
    const float* Wv  = (const float*)d_in[6];
    const float* bv  = (const float*)d_in[7];
    const float* g0  = (const float*)d_in[8];
    const float* be0 = (const float*)d_in[9];
    const float* g1  = (const float*)d_in[10];
    const float* be1 = (const float*)d_in[11];
    const float* W12 = (const float*)d_in[12];
    const float* b12 = (const float*)d_in[13];
    const float* W3  = (const float*)d_in[14];
    const float* b3  = (const float*)d_in[15];

    // fp32 region (80 MB): Qp, Oa, Oln, x12(32MB)
    float* ws   = (float*)d_ws;
    float* Qp   = ws;                    // [4096,1024]
    float* Oa   = ws + (1u << 22);
    float* Oln  = ws + (2u << 22);
    float* x12  = ws + (3u << 22);       // [4096,2048] (32 MB)

    // attention-proj weight splits overlay x12 (dead until FFN)
    ushort* wsm   = (ushort*)(ws + (3u << 22));
    ushort* Wqhi  = wsm;                 // 1M us each
    ushort* Wqlo  = wsm + (1u << 20);
    ushort* Wkhi  = wsm + (2u << 20);
    ushort* Wklo  = wsm + (3u << 20);
    ushort* Wvhi  = wsm + (4u << 20);
    ushort* Wvlo  = wsm + (5u << 20);

    // ushort region after fp32 (slots of 4M us = 8 MB)
    ushort* u     = (ushort*)(ws + (5u << 22));
    ushort* QpHi  = u;                   // s0
    ushort* KpHi  = u + (1u << 22);      // s1
    ushort* Qhi   = u + (2u << 22);      // s2
    ushort* Qlo   = u + (3u << 22);      // s3
    ushort* Khi   = u + (4u << 22);      // s4
    ushort* Klo   = u + (5u << 22);      // s5
    ushort* Vt    = u + (6u << 22);      // s6  [64][64][1024]
    ushort* OlnHi = Qhi;                 // reuse (dead after Q-proj)
    ushort* OlnLo = Qlo;
    ushort* GHi   = Khi;                 // reuse (dead after V-proj)
    ushort* GLo   = Klo;
    ushort* W12hi = u + (7u << 22);      // 2M us
    ushort* W12lo = W12hi + (1u << 21);
    ushort* W3hi  = W12hi + (2u << 21);  // 1M us
    ushort* W3lo  = W12hi + (3u << 21);
    // total: 80 + 56 + 12 = 148 MB  (validated available in r5/r8)

    float* Oout = (float*)d_out;                 // [4,1024,1024]
    float* Aout = Oout + (1u << 22);             // [64,1024,1024]

    const dim3 blk(256);

    // 0: splits
    split_bf<<<4096, blk, 0, stream>>>(Q,   Qhi,   Qlo,   1 << 20);
    split_bf<<<4096, blk, 0, stream>>>(K,   Khi,   Klo,   1 << 20);
    split_bf<<<1024, blk, 0, stream>>>(Wq,  Wqhi,  Wqlo,  1 << 18);
    split_bf<<<1024, blk, 0, stream>>>(Wk,  Wkhi,  Wklo,  1 << 18);
    split_bf<<<1024, blk, 0, stream>>>(Wv,  Wvhi,  Wvlo,  1 << 18);
    split_bf<<<2048, blk, 0, stream>>>(W12, W12hi, W12lo, 1 << 19);
    split_bf<<<1024, blk, 0, stream>>>(W3,  W3hi,  W3lo,  1 << 18);

    // 1-3: projections (64x64 tiles -> 1024 blocks, 4 blocks/CU).
    gemm_mfma<3,1,0,1><<<dim3(64,16), blk, 0, stream>>>(
        Qhi, Qlo, DIM, Wqhi, Wqlo, DIM, bq, nullptr, Qp, QpHi, DIM, DIM, 1.f);
    gemm_mfma<3,1,0,2><<<dim3(64,16), blk, 0, stream>>>(
        Khi, Klo, DIM, Wkhi, Wklo, DIM, bk, nullptr, nullptr, KpHi, DIM, DIM, 1.f);
    gemm_mfma<3,1,0,3><<<dim3(64,16), blk, 0, stream>>>(
        Khi, Klo, DIM, Wvhi, Wvlo, DIM, bv, nullptr, nullptr, Vt, DIM, DIM, 1.f);

    // 4: flash attention: writes A (d_out) once + Oa = Qp + P.V
    flash_attn<<<dim3(8,64), blk, 0, stream>>>(QpHi, KpHi, Vt, Qp, Aout, Oa);

    // 5: LN0 (+ bf16 split for FFN)
    ln_rows<1><<<4096, blk, 0, stream>>>(Oa, g0, be0, Oln, OlnHi, OlnLo);

    // 6: x12 = Oln * W12^T + b12   (2048 blocks)
    gemm_mfma<3,1,0,0><<<dim3(64,32), blk, 0, stream>>>(
        OlnHi, OlnLo, DIM, W12hi, W12lo, DIM, b12, nullptr, x12, nullptr, 2048, DIM, 1.f);

    // 7: gate = silu(x1)*x2 -> bf16 hi/lo
    silu_mul<<<4096, blk, 0, stream>>>(x12, GHi, GLo);

    // 8: Oa = Oln + gate * W3^T + b3
    gemm_mfma<3,1,1,0><<<dim3(64,16), blk, 0, stream>>>(
        GHi, GLo, DIM, W3hi, W3lo, DIM, b3, Oln, Oa, nullptr, DIM, DIM, 1.f);

    // 9: LN1 -> final O
    ln_rows<0><<<4096, blk, 0, stream>>>(Oa, g1, be1, Oout, nullptr, nullptr);
}